// Round 20
// baseline (1258.359 us; speedup 1.0000x reference)
//
#include <hip/hip_runtime.h>

// Problem constants: B=64, T=256, V=4096, H=512
// Inputs: x[B*T] i32, Wxh[V,H] f32, Whh[H,H] f32, bh[H] f32, Wo[H,V] f32, Bo[V] f32
// Output: out[B,T,V] f32 = (scan hs) @ Wo + Bo

typedef __fp16 half2_t __attribute__((ext_vector_type(2)));
typedef __attribute__((ext_vector_type(8))) short short8;   // 8 bf16 (MFMA A/B frag)
typedef __attribute__((ext_vector_type(4))) float f32x4;    // MFMA C/D frag

__device__ __forceinline__ unsigned short f32_to_bf16(float f) {
  unsigned int u = __builtin_bit_cast(unsigned int, f);
  u = (u + 0x7FFFu + ((u >> 16) & 1u)) >> 16;  // RNE
  return (unsigned short)u;
}

__device__ __forceinline__ unsigned int pack_f16x2(float a, float b) {
  half2_t h = __builtin_amdgcn_cvt_pkrtz(a, b);
  return __builtin_bit_cast(unsigned int, h);
}

__device__ __forceinline__ float fdot2_(unsigned int w, unsigned int h, float acc) {
  return __builtin_amdgcn_fdot2(__builtin_bit_cast(half2_t, w),
                                __builtin_bit_cast(half2_t, h), acc, false);
}

__device__ __forceinline__ void glds16(const void* g, void* lds) {
  __builtin_amdgcn_global_load_lds(
      (const __attribute__((address_space(1))) unsigned int*)g,
      (__attribute__((address_space(3))) unsigned int*)lds, 16, 0, 0);
}

// ---------------------------------------------------------------------------
// Prep 1: Whh -> WhhB per-slice LDS image (R14/R15/R17 layout, f16). u32 flat
// idx = G*4+e, G = ((s*4 + q)*16 + u)*128 + c: f16 pair p = q*64 + u*4 + e of
// column j = s*128 + c  (in-scan chunk kc = q*16+u: wlds[kc*128+c] holds
// pairs [4kc,4kc+4) of column s*128+c). Zeroes hG64 tags every launch.
// ---------------------------------------------------------------------------
__global__ __launch_bounds__(256) void pack_whhB(const float* __restrict__ Whh,
                                                 unsigned int* __restrict__ WhhB,
                                                 unsigned long long* __restrict__ hG64) {
  int idx = blockIdx.x * 256 + threadIdx.x;  // 131072 threads
  int e = idx & 3;
  int G = idx >> 2;
  int c = G & 127;
  int u = (G >> 7) & 15;
  int q = (G >> 11) & 3;
  int s = G >> 13;
  int p = q * 64 + u * 4 + e;   // f16-pair index 0..255
  int j = s * 128 + c;          // column
  float f0 = Whh[(2 * p) * 512 + j];
  float f1 = Whh[(2 * p + 1) * 512 + j];
  WhhB[idx] = pack_f16x2(f0, f1);
  if (idx < 32768) hG64[idx] = 0ull;  // tag 0 != any target t>=1
}

// ---------------------------------------------------------------------------
// Prep 2: Wo [h][v] f32 -> WoT [v][h] bf16
// ---------------------------------------------------------------------------
__global__ __launch_bounds__(256) void transpose_wo(const float* __restrict__ Wo,
                                                    unsigned short* __restrict__ WoT) {
  __shared__ float tile[64][65];
  const int tv = blockIdx.x;   // 0..63  (V/64)
  const int th = blockIdx.y;   // 0..7   (H/64)
  const int tid = threadIdx.x;
  const int c = tid & 63, r4 = tid >> 6;
#pragma unroll
  for (int p = 0; p < 16; ++p) {
    int hl = p * 4 + r4;
    tile[hl][c] = Wo[(size_t)(th * 64 + hl) * 4096 + tv * 64 + c];
  }
  __syncthreads();
#pragma unroll
  for (int p = 0; p < 16; ++p) {
    int vl = p * 4 + r4;
    WoT[(size_t)(tv * 64 + vl) * 512 + th * 64 + c] = f32_to_bf16(tile[c][vl]);
  }
}

// ---------------------------------------------------------------------------
// Recurrence vG: 4-BATCH INTERLEAVE -- hide the sync chain, don't shorten it.
// R17 analysis: step = dots 1100 + finalize 700 + sync wait ~2000 (CU idle
// >50%). Fix: 64 blocks = 16 groups x 4 slices; each block holds slice s
// (f16, 128 KB LDS -- R19 showed e5m2's unpack VALU loses on the serialized
// path) for FOUR batches b0..b0+3 and round-robins them. While batch n's
// tagged store propagates (~2000 cyc), the CU computes the other 3 batches
// (~3x1650 cyc >> chain) -> compute-bound, ~1650 cyc/step amortized.
// Poll words are PREFETCHED one phase early into a register (atomic load
// issued then consumed next phase; spin-fallback on tag mismatch, so
// correctness never depends on the hit). Per-batch protocol byte-identical
// to R15/R17: tagged u64 (tag t+1 | 2xf16 pre-tanh u), parity double-buffer,
// tags zeroed per launch; anti-drift invariant carries over per batch.
// ---------------------------------------------------------------------------
#define DOTK(hb_, kc_, A) do { \
  const uint4 w_ = wlds[(kc_) * 128 + c]; \
  const uint4 h_ = hb_[(kc_)]; \
  A = fdot2_(w_.x, h_.x, A); A = fdot2_(w_.y, h_.y, A); \
  A = fdot2_(w_.z, h_.z, A); A = fdot2_(w_.w, h_.w, A); } while (0)

__global__ __launch_bounds__(512) void rnn_scanG(const int* __restrict__ x,
                                                 const float* __restrict__ Wxh,
                                                 const unsigned int* __restrict__ WhhB,
                                                 const float* __restrict__ bh,
                                                 unsigned short* __restrict__ hs,
                                                 unsigned long long* hG64) {
  __shared__ uint4 wlds[8192];      // 128 KB: this block's f16 weight slice
  __shared__ uint4 hbuf4[4][64];    // 4 batches x 512 h (f16 pairs)
  __shared__ float pbuf[4][512];    // 4 batches x partials [q][c]
  __shared__ int toks[1024];        // 4 batches x 256 tokens
  const int bid = blockIdx.x;       // 0..63
  const int s = bid & 3;            // column-slice
  const int grp = bid >> 2;         // batch-group 0..15
  const int b0 = grp * 4;           // first batch of the group
  const int tid = threadIdx.x;
  const int c = tid & 127;
  const int q = tid >> 7;           // k-phase (chunks kc == q mod 4)
  const uint4* W4 = (const uint4*)WhhB;

  // stage this block's 128 KB weight slice (coalesced, 16 rounds)
#pragma unroll
  for (int it = 0; it < 16; ++it) {
    int L = it * 512 + tid;
    wlds[L] = W4[s * 8192 + L];
  }
  if (tid < 256) {  // h0 = 0 for all 4 batches
    ((uint4*)hbuf4)[tid] = make_uint4(0u, 0u, 0u, 0u);
  }
  for (int i = tid; i < 1024; i += 512) toks[i] = x[b0 * 256 + i];
  __syncthreads();

  const float bhj = (tid < 128) ? bh[s * 128 + tid] : 0.f;
  // poll-slot for this thread (tid<192): slot index within the 256, skipping own slice
  const int rslot = (tid < s * 64) ? tid : tid + 64;

  unsigned long long vpre = 0ull;   // prefetched poll word (phase pipeline)

  for (int t = 0; t < 256; ++t) {
#pragma unroll
    for (int n = 0; n < 4; ++n) {
      const int b = b0 + n;
      unsigned int* hb32 = (unsigned int*)hbuf4[n];
      const uint4* hb = hbuf4[n];

      const int tok = toks[n * 256 + t];
      const float xv = (tid < 128) ? Wxh[(size_t)tok * 512 + s * 128 + tid] : 0.f;

      if (t > 0 && tid < 192) {
        // consume prefetched word; spin-fallback if sibling is behind
        const unsigned long long* src =
            hG64 + (((size_t)(t & 1)) << 14) + b * 256 + rslot;
        unsigned long long v = vpre;
        while ((unsigned)(v >> 32) != (unsigned)t)
          v = __hip_atomic_load(src, __ATOMIC_RELAXED, __HIP_MEMORY_SCOPE_AGENT);
        half2_t up = __builtin_bit_cast(half2_t, (unsigned)v);
        hb32[rslot] = pack_f16x2(tanhf((float)up.x), tanhf((float)up.y));
      }
      // prefetch next phase's poll word (batch n+1, or batch 0 of t+1);
      // issued now so its ~500cyc LLC latency hides under this phase's dots
      if (tid < 192) {
        const int nn = (n + 1) & 3;
        const int tt = (n == 3) ? (t + 1) : t;
        const unsigned long long* psrc =
            hG64 + (((size_t)(tt & 1)) << 14) + (b0 + nn) * 256 + rslot;
        vpre = __hip_atomic_load(psrc, __ATOMIC_RELAXED, __HIP_MEMORY_SCOPE_AGENT);
      }
      __syncthreads();  // hbuf4[n] remote entries ready

      float a0 = 0.f, a1 = 0.f, a2 = 0.f, a3 = 0.f;
#pragma unroll
      for (int i = 0; i < 4; ++i) {
        DOTK(hb, 16 * i + 0 * 4 + q, a0);
        DOTK(hb, 16 * i + 1 * 4 + q, a1);
        DOTK(hb, 16 * i + 2 * 4 + q, a2);
        DOTK(hb, 16 * i + 3 * 4 + q, a3);
      }
      pbuf[n][q * 128 + c] = (a0 + a1) + (a2 + a3);
      __syncthreads();

      // finalize: 128 threads x 1 col; store tagged pre-tanh u FIRST
      if (tid < 128) {
        const float ssum = pbuf[n][tid] + pbuf[n][tid + 128] +
                           pbuf[n][tid + 256] + pbuf[n][tid + 384];
        const float u1 = xv + ssum + bhj;
        const float u2 = __shfl_down(u1, 1);  // odd partner's u
        if (!(tid & 1)) {
          const unsigned int up = pack_f16x2(u1, u2);
          __hip_atomic_store(
              hG64 + (((size_t)((t + 1) & 1)) << 14) + b * 256 + 64 * s + (tid >> 1),
              ((unsigned long long)(unsigned)(t + 1) << 32) | up,
              __ATOMIC_RELAXED, __HIP_MEMORY_SCOPE_AGENT);
          // own h from the SAME rounded u (bit-consistent with readers)
          half2_t uo = __builtin_bit_cast(half2_t, up);
          const float h1 = tanhf((float)uo.x);
          const float h2 = tanhf((float)uo.y);
          hb32[64 * s + (tid >> 1)] = pack_f16x2(h1, h2);
          ((unsigned int*)hs)[(size_t)(b * 256 + t) * 256 + 64 * s + (tid >> 1)] =
              (unsigned int)f32_to_bf16(h1) | ((unsigned int)f32_to_bf16(h2) << 16);
        }
      }
      // no barrier needed here: batch n+1's poll barrier orders everything;
      // hbuf4[n]/pbuf[n] next touched a full superstep away (>=8 barriers).
    }
  }
}

// ---------------------------------------------------------------------------
// Output GEMM: C[16384,4096] = A[16384,512](bf16) @ WoT^T + Bo.  m97 structure.
// ---------------------------------------------------------------------------
__global__ __launch_bounds__(256) void gemm_out(const unsigned short* __restrict__ A,
                                                const unsigned short* __restrict__ Bt,
                                                const float* __restrict__ Bo,
                                                float* __restrict__ C) {
  __shared__ alignas(16) unsigned short As[128 * 32];
  __shared__ alignas(16) unsigned short Bs[128 * 32];
  const int tid = threadIdx.x;
  const int lane = tid & 63, wid = tid >> 6;
  const int bn = blockIdx.x & 31, bm = blockIdx.x >> 5;
  const int wr = wid >> 1, wc = wid & 1;

  f32x4 acc[4][4] = {};

  const unsigned short* Ag = A + (size_t)(bm * 128 + (tid >> 2)) * 512 + (tid & 3) * 8;
  const unsigned short* Bg = Bt + (size_t)(bn * 128 + (tid >> 2)) * 512 + (tid & 3) * 8;
  char* AsW = (char*)As + wid * 1024;
  char* BsW = (char*)Bs + wid * 1024;

  const int laneRow = lane & 15;
  const int k0 = (lane >> 4) * 8;

  for (int kt = 0; kt < 16; ++kt) {
    __syncthreads();
    const unsigned short* a0 = Ag + kt * 32;
    const unsigned short* b0 = Bg + kt * 32;
    glds16(a0,            AsW);
    glds16(a0 + 64 * 512, AsW + 4096);
    glds16(b0,            BsW);
    glds16(b0 + 64 * 512, BsW + 4096);
    __syncthreads();

    short8 af[4], bf[4];
#pragma unroll
    for (int f = 0; f < 4; ++f)
      af[f] = *(const short8*)&As[(wr * 64 + f * 16 + laneRow) * 32 + k0];
#pragma unroll
    for (int f = 0; f < 4; ++f)
      bf[f] = *(const short8*)&Bs[(wc * 64 + f * 16 + laneRow) * 32 + k0];
#pragma unroll
    for (int fm = 0; fm < 4; ++fm)
#pragma unroll
      for (int fn = 0; fn < 4; ++fn)
        acc[fm][fn] = __builtin_amdgcn_mfma_f32_16x16x32_bf16(af[fm], bf[fn], acc[fm][fn], 0, 0, 0);
  }

  const int mg0 = bm * 128 + wr * 64, ng0 = bn * 128 + wc * 64;
#pragma unroll
  for (int fn = 0; fn < 4; ++fn) {
    const int col = ng0 + fn * 16 + laneRow;
    const float bo = Bo[col];
#pragma unroll
    for (int fm = 0; fm < 4; ++fm) {
      const int row0 = mg0 + fm * 16 + (lane >> 4) * 4;
#pragma unroll
      for (int r = 0; r < 4; ++r)
        C[(size_t)(row0 + r) * 4096 + col] = acc[fm][fn][r] + bo;
    }
  }
}

// ---------------------------------------------------------------------------
extern "C" void kernel_launch(void* const* d_in, const int* in_sizes, int n_in,
                              void* d_out, int out_size, void* d_ws, size_t ws_size,
                              hipStream_t stream) {
  (void)in_sizes; (void)n_in; (void)out_size; (void)ws_size;
  const int* x = (const int*)d_in[0];
  const float* Wxh = (const float*)d_in[1];
  const float* Whh = (const float*)d_in[2];
  const float* bh = (const float*)d_in[3];
  const float* Wo = (const float*)d_in[4];
  const float* Bo = (const float*)d_in[5];
  float* out = (float*)d_out;

  // workspace map (bytes):
  //   WhhB   @ 0         512 KB
  //   WoT    @ 524288    4 MB
  //   hs     @ 4718592   16 MB
  //   hG64   @ 21495808  256 KB   (2 x 64 x 256 tagged u64)
  unsigned int* WhhB = (unsigned int*)d_ws;
  unsigned short* WoT = (unsigned short*)((char*)d_ws + 524288);
  unsigned short* hs = (unsigned short*)((char*)d_ws + 4718592);
  unsigned long long* hG64 = (unsigned long long*)((char*)d_ws + 21495808);

  hipLaunchKernelGGL(pack_whhB, dim3(512), dim3(256), 0, stream, Whh, WhhB, hG64);
  hipLaunchKernelGGL(transpose_wo, dim3(64, 8), dim3(256), 0, stream, Wo, WoT);
  hipLaunchKernelGGL(rnn_scanG, dim3(64), dim3(512), 0, stream, x, Wxh, WhhB, bh,
                     hs, hG64);
  hipLaunchKernelGGL(gemm_out, dim3(4096), dim3(256), 0, stream, hs, WoT, Bo, out);
}

// Round 21
// 518.273 us; speedup vs baseline: 2.4280x; 2.4280x over previous
//
#include <hip/hip_runtime.h>

// Problem constants: B=64, T=256, V=4096, H=512
// Inputs: x[B*T] i32, Wxh[V,H] f32, Whh[H,H] f32, bh[H] f32, Wo[H,V] f32, Bo[V] f32
// Output: out[B,T,V] f32 = (scan hs) @ Wo + Bo
//
// === R21: deliberate revert to the R17 champion (517.8 us, scan 424 us) ===
// R18 (2-way split + e5m2), R19 (e5m2 LDS), R20 (4-batch interleave) all
// regressed for understood reasons: work concentration lengthens the serial
// chain; unpack VALU on the serialized path loses; batch dim is already fully
// spent on CU-parallelism so there is no spare work to hide sync latency.
// Structural accounting of this version: 256 sequential steps x
// (LLC tagged-exchange RT ~1500-2000 cyc + LDS dots/finalize ~1900 cyc).

typedef __fp16 half2_t __attribute__((ext_vector_type(2)));
typedef __attribute__((ext_vector_type(8))) short short8;   // 8 bf16 (MFMA A/B frag)
typedef __attribute__((ext_vector_type(4))) float f32x4;    // MFMA C/D frag

__device__ __forceinline__ unsigned short f32_to_bf16(float f) {
  unsigned int u = __builtin_bit_cast(unsigned int, f);
  u = (u + 0x7FFFu + ((u >> 16) & 1u)) >> 16;  // RNE
  return (unsigned short)u;
}

__device__ __forceinline__ unsigned int pack_f16x2(float a, float b) {
  half2_t h = __builtin_amdgcn_cvt_pkrtz(a, b);
  return __builtin_bit_cast(unsigned int, h);
}

__device__ __forceinline__ float fdot2_(unsigned int w, unsigned int h, float acc) {
  return __builtin_amdgcn_fdot2(__builtin_bit_cast(half2_t, w),
                                __builtin_bit_cast(half2_t, h), acc, false);
}

__device__ __forceinline__ void glds16(const void* g, void* lds) {
  __builtin_amdgcn_global_load_lds(
      (const __attribute__((address_space(1))) unsigned int*)g,
      (__attribute__((address_space(3))) unsigned int*)lds, 16, 0, 0);
}

// ---------------------------------------------------------------------------
// Prep 1: Whh -> WhhB per-slice LDS image. u32 flat idx = G*4+e,
// G = ((s*4 + q)*16 + u)*128 + c: f16 pair p = q*64 + u*4 + e of column
// j = s*128 + c  (in-scan chunk kc = q*16+u: wlds[kc*128+c] holds pairs
// [4kc,4kc+4) of column s*128+c). Zeroes hG64 tags every launch (graph
// replays rerun this kernel -> stale tags can never alias).
// ---------------------------------------------------------------------------
__global__ __launch_bounds__(256) void pack_whhB(const float* __restrict__ Whh,
                                                 unsigned int* __restrict__ WhhB,
                                                 unsigned long long* __restrict__ hG64) {
  int idx = blockIdx.x * 256 + threadIdx.x;  // 131072 threads
  int e = idx & 3;
  int G = idx >> 2;
  int c = G & 127;
  int u = (G >> 7) & 15;
  int q = (G >> 11) & 3;
  int s = G >> 13;
  int p = q * 64 + u * 4 + e;   // f16-pair index 0..255
  int j = s * 128 + c;          // column
  float f0 = Whh[(2 * p) * 512 + j];
  float f1 = Whh[(2 * p + 1) * 512 + j];
  WhhB[idx] = pack_f16x2(f0, f1);
  if (idx < 32768) hG64[idx] = 0ull;  // tag 0 != any target t>=1
}

// ---------------------------------------------------------------------------
// Prep 2: Wo [h][v] f32 -> WoT [v][h] bf16
// ---------------------------------------------------------------------------
__global__ __launch_bounds__(256) void transpose_wo(const float* __restrict__ Wo,
                                                    unsigned short* __restrict__ WoT) {
  __shared__ float tile[64][65];
  const int tv = blockIdx.x;   // 0..63  (V/64)
  const int th = blockIdx.y;   // 0..7   (H/64)
  const int tid = threadIdx.x;
  const int c = tid & 63, r4 = tid >> 6;
#pragma unroll
  for (int p = 0; p < 16; ++p) {
    int hl = p * 4 + r4;
    tile[hl][c] = Wo[(size_t)(th * 64 + hl) * 4096 + tv * 64 + c];
  }
  __syncthreads();
#pragma unroll
  for (int p = 0; p < 16; ++p) {
    int vl = p * 4 + r4;
    WoT[(size_t)(tv * 64 + vl) * 512 + th * 64 + c] = f32_to_bf16(tile[c][vl]);
  }
}

// ---------------------------------------------------------------------------
// Recurrence vD (champion): weights 100% LDS-resident, 4 blocks/batch,
// tagged-u64 LLC exchange (R15 protocol), three critical-chain trims:
//  (1) xv prefetch at loop top
//  (2) interleaved k-walk: own-quarter chunks (local h) computed BEFORE
//      polling -> ~25% of dots overlap the store->visibility window
//  (3) finalize: 128 thr x 1 col, tagged PRE-TANH u stored first; readers
//      tanh on receipt; writer re-derives own h from the same rounded u.
// ---------------------------------------------------------------------------
#define DOTK(kc_, A) do { \
  const uint4 w_ = wlds[(kc_) * 128 + c]; \
  const uint4 h_ = hbuf[(kc_)]; \
  A = fdot2_(w_.x, h_.x, A); A = fdot2_(w_.y, h_.y, A); \
  A = fdot2_(w_.z, h_.z, A); A = fdot2_(w_.w, h_.w, A); } while (0)

__global__ __launch_bounds__(512) void rnn_scanD(const int* __restrict__ x,
                                                 const float* __restrict__ Wxh,
                                                 const unsigned int* __restrict__ WhhB,
                                                 const float* __restrict__ bh,
                                                 unsigned short* __restrict__ hs,
                                                 unsigned long long* hG64) {
  __shared__ uint4 wlds[8192];   // 128 KB: this block's full weight slice
  __shared__ uint4 hbuf[64];     // 512 h values as f16 pairs
  __shared__ float pbuf[512];    // partials [q][c]
  __shared__ int toks[256];
  const int bid = blockIdx.x;
  const int s = bid & 3;         // column-slice (R15 mapping, proven)
  const int b = bid >> 2;        // batch
  const int tid = threadIdx.x;
  const int c = tid & 127;
  const int q = tid >> 7;        // k-phase within each quarter
  const int s16 = s * 16;
  const uint4* W4 = (const uint4*)WhhB;

  // stage this block's 128 KB weight slice (coalesced, 16 rounds)
#pragma unroll
  for (int it = 0; it < 16; ++it) {
    int L = it * 512 + tid;
    wlds[L] = W4[s * 8192 + L];
  }
  if (tid < 64) hbuf[tid] = make_uint4(0u, 0u, 0u, 0u);  // h0 = 0
  if (tid < 256) toks[tid] = x[b * 256 + tid];
  __syncthreads();

  unsigned int* hb32 = (unsigned int*)hbuf;      // [256] u32 view of h pairs
  const float bhj = (tid < 128) ? bh[s * 128 + tid] : 0.f;

  for (int t = 0; t < 256; ++t) {
    const int tok = toks[t];
    // (1) prefetch xv now; resolved long before finalize uses it
    const float xv = (tid < 128) ? Wxh[(size_t)tok * 512 + s * 128 + tid] : 0.f;

    float a0 = 0.f, a1 = 0.f, a2 = 0.f, a3 = 0.f;
    // (2) phase 1: own-quarter chunks (h from local write last step) --
    // overlaps the siblings' store->LLC-visibility window
    DOTK(s16 + 0 + q, a0); DOTK(s16 + 4 + q, a1);
    DOTK(s16 + 8 + q, a2); DOTK(s16 + 12 + q, a3);

    if (t > 0 && tid < 192) {
      // pull 192 remote u-pairs: spin on own tagged word, tanh on receipt
      const int r = (tid < s * 64) ? tid : tid + 64;  // skip own slice
      const unsigned long long* src =
          hG64 + (((size_t)(t & 1)) << 14) + b * 256 + r;
      unsigned long long v;
      do {
        v = __hip_atomic_load(src, __ATOMIC_RELAXED, __HIP_MEMORY_SCOPE_AGENT);
      } while ((unsigned)(v >> 32) != (unsigned)t);
      half2_t up = __builtin_bit_cast(half2_t, (unsigned)v);
      hb32[r] = pack_f16x2(tanhf((float)up.x), tanhf((float)up.y));
    }
    __syncthreads();

    // phase 2: the three remote quarters
    {
      int m1 = ((s + 1) & 3) * 16;
      DOTK(m1 + 0 + q, a0); DOTK(m1 + 4 + q, a1);
      DOTK(m1 + 8 + q, a2); DOTK(m1 + 12 + q, a3);
      int m2 = ((s + 2) & 3) * 16;
      DOTK(m2 + 0 + q, a0); DOTK(m2 + 4 + q, a1);
      DOTK(m2 + 8 + q, a2); DOTK(m2 + 12 + q, a3);
      int m3 = ((s + 3) & 3) * 16;
      DOTK(m3 + 0 + q, a0); DOTK(m3 + 4 + q, a1);
      DOTK(m3 + 8 + q, a2); DOTK(m3 + 12 + q, a3);
    }
    pbuf[q * 128 + c] = (a0 + a1) + (a2 + a3);
    __syncthreads();

    // (3) finalize: 128 threads x 1 col; store tagged pre-tanh u FIRST
    if (tid < 128) {
      const float ssum = pbuf[tid] + pbuf[tid + 128] + pbuf[tid + 256] + pbuf[tid + 384];
      const float u1 = xv + ssum + bhj;
      const float u2 = __shfl_down(u1, 1);  // odd partner's u (pair in-wave)
      if (!(tid & 1)) {
        const unsigned int up = pack_f16x2(u1, u2);
        __hip_atomic_store(
            hG64 + (((size_t)((t + 1) & 1)) << 14) + b * 256 + 64 * s + (tid >> 1),
            ((unsigned long long)(unsigned)(t + 1) << 32) | up,
            __ATOMIC_RELAXED, __HIP_MEMORY_SCOPE_AGENT);
        // own h from the SAME rounded u (bit-consistent with readers)
        half2_t uo = __builtin_bit_cast(half2_t, up);
        const float h1 = tanhf((float)uo.x);
        const float h2 = tanhf((float)uo.y);
        hb32[64 * s + (tid >> 1)] = pack_f16x2(h1, h2);
        ((unsigned int*)hs)[(size_t)(b * 256 + t) * 256 + 64 * s + (tid >> 1)] =
            (unsigned int)f32_to_bf16(h1) | ((unsigned int)f32_to_bf16(h2) << 16);
      }
    }
    __syncthreads();  // own-slice LDS update visible; pbuf reusable
  }
}

// ---------------------------------------------------------------------------
// Output GEMM: C[16384,4096] = A[16384,512](bf16) @ WoT^T + Bo.  m97 structure.
// ---------------------------------------------------------------------------
__global__ __launch_bounds__(256) void gemm_out(const unsigned short* __restrict__ A,
                                                const unsigned short* __restrict__ Bt,
                                                const float* __restrict__ Bo,
                                                float* __restrict__ C) {
  __shared__ alignas(16) unsigned short As[128 * 32];
  __shared__ alignas(16) unsigned short Bs[128 * 32];
  const int tid = threadIdx.x;
  const int lane = tid & 63, wid = tid >> 6;
  const int bn = blockIdx.x & 31, bm = blockIdx.x >> 5;
  const int wr = wid >> 1, wc = wid & 1;

  f32x4 acc[4][4] = {};

  const unsigned short* Ag = A + (size_t)(bm * 128 + (tid >> 2)) * 512 + (tid & 3) * 8;
  const unsigned short* Bg = Bt + (size_t)(bn * 128 + (tid >> 2)) * 512 + (tid & 3) * 8;
  char* AsW = (char*)As + wid * 1024;
  char* BsW = (char*)Bs + wid * 1024;

  const int laneRow = lane & 15;
  const int k0 = (lane >> 4) * 8;

  for (int kt = 0; kt < 16; ++kt) {
    __syncthreads();
    const unsigned short* a0 = Ag + kt * 32;
    const unsigned short* b0 = Bg + kt * 32;
    glds16(a0,            AsW);
    glds16(a0 + 64 * 512, AsW + 4096);
    glds16(b0,            BsW);
    glds16(b0 + 64 * 512, BsW + 4096);
    __syncthreads();

    short8 af[4], bf[4];
#pragma unroll
    for (int f = 0; f < 4; ++f)
      af[f] = *(const short8*)&As[(wr * 64 + f * 16 + laneRow) * 32 + k0];
#pragma unroll
    for (int f = 0; f < 4; ++f)
      bf[f] = *(const short8*)&Bs[(wc * 64 + f * 16 + laneRow) * 32 + k0];
#pragma unroll
    for (int fm = 0; fm < 4; ++fm)
#pragma unroll
      for (int fn = 0; fn < 4; ++fn)
        acc[fm][fn] = __builtin_amdgcn_mfma_f32_16x16x32_bf16(af[fm], bf[fn], acc[fm][fn], 0, 0, 0);
  }

  const int mg0 = bm * 128 + wr * 64, ng0 = bn * 128 + wc * 64;
#pragma unroll
  for (int fn = 0; fn < 4; ++fn) {
    const int col = ng0 + fn * 16 + laneRow;
    const float bo = Bo[col];
#pragma unroll
    for (int fm = 0; fm < 4; ++fm) {
      const int row0 = mg0 + fm * 16 + (lane >> 4) * 4;
#pragma unroll
      for (int r = 0; r < 4; ++r)
        C[(size_t)(row0 + r) * 4096 + col] = acc[fm][fn][r] + bo;
    }
  }
}

// ---------------------------------------------------------------------------
extern "C" void kernel_launch(void* const* d_in, const int* in_sizes, int n_in,
                              void* d_out, int out_size, void* d_ws, size_t ws_size,
                              hipStream_t stream) {
  (void)in_sizes; (void)n_in; (void)out_size; (void)ws_size;
  const int* x = (const int*)d_in[0];
  const float* Wxh = (const float*)d_in[1];
  const float* Whh = (const float*)d_in[2];
  const float* bh = (const float*)d_in[3];
  const float* Wo = (const float*)d_in[4];
  const float* Bo = (const float*)d_in[5];
  float* out = (float*)d_out;

  // workspace map (bytes):
  //   WhhB   @ 0         512 KB
  //   WoT    @ 524288    4 MB
  //   hs     @ 4718592   16 MB
  //   hG64   @ 21495808  256 KB   (2 x 64 x 256 tagged u64)
  unsigned int* WhhB = (unsigned int*)d_ws;
  unsigned short* WoT = (unsigned short*)((char*)d_ws + 524288);
  unsigned short* hs = (unsigned short*)((char*)d_ws + 4718592);
  unsigned long long* hG64 = (unsigned long long*)((char*)d_ws + 21495808);

  hipLaunchKernelGGL(pack_whhB, dim3(512), dim3(256), 0, stream, Whh, WhhB, hG64);
  hipLaunchKernelGGL(transpose_wo, dim3(64, 8), dim3(256), 0, stream, Wo, WoT);
  hipLaunchKernelGGL(rnn_scanD, dim3(256), dim3(512), 0, stream, x, Wxh, WhhB, bh,
                     hs, hG64);
  hipLaunchKernelGGL(gemm_out, dim3(4096), dim3(256), 0, stream, hs, WoT, Bo, out);
}